// Round 15
// baseline (92.303 us; speedup 1.0000x reference)
//
#include <hip/hip_runtime.h>

#define NB 8
#define CQ 128
#define CKV 64
#define NPIX 4096
#define QDIM 16
#define KVBLK 256
#define NTI (NPIX / KVBLK)   // 16 tiles of 256 keys

typedef float f32x4 __attribute__((ext_vector_type(4)));
typedef float f32x16 __attribute__((ext_vector_type(16)));
typedef __bf16 bf16x8 __attribute__((ext_vector_type(8)));
typedef unsigned short u16;
typedef u16 u16x4 __attribute__((ext_vector_type(4)));
typedef unsigned int u32;
typedef u32 u32x2 __attribute__((ext_vector_type(2)));
typedef u32 u32x4 __attribute__((ext_vector_type(4)));

static __device__ __forceinline__ u16 f2bf(float f) {
  unsigned int u = __builtin_bit_cast(unsigned int, f);
  u = (u + 0x7FFFu + ((u >> 16) & 1u)) >> 16;
  return (u16)u;
}
static __device__ __forceinline__ u32 cvtpk(float lo, float hi) {
  u32 r; asm("v_cvt_pk_bf16_f32 %0, %1, %2" : "=v"(r) : "v"(lo), "v"(hi)); return r;
}
static __device__ __forceinline__ void plswap(u32& a, u32& b) {
#if __has_builtin(__builtin_amdgcn_permlane32_swap)
  u32x2 r = __builtin_amdgcn_permlane32_swap(a, b, false, false);
  a = r[0]; b = r[1];
#else
  asm volatile("v_permlane32_swap_b32 %0, %1" : "+v"(a), "+v"(b));
#endif
}
// async global->LDS, 16B per lane; LDS dest = uniform base + lane*16 (per-lane global src)
static __device__ __forceinline__ void gload_lds16(const void* g, void* l) {
  __builtin_amdgcn_global_load_lds((const __attribute__((address_space(1))) void*)g,
                                   (__attribute__((address_space(3))) void*)l, 16, 0, 0);
}

// ---- merged q,k,v projections: blocks [0,512) do q/k, blocks [512,1024) do v ----
__global__ __launch_bounds__(256) void proj_qkv(
    const float* __restrict__ xq, const float* __restrict__ Wq, const float* __restrict__ bq,
    const float* __restrict__ xkv, const float* __restrict__ Wk, const float* __restrict__ bk,
    const float* __restrict__ Wv, const float* __restrict__ bv,
    u16* __restrict__ Qs, u16* __restrict__ Ks, u16* __restrict__ Vt)
{
  __shared__ __align__(16) char smem[50688];
  int t = threadIdx.x;
  if ((int)blockIdx.x < NB * 64) {
    int bid = (int)blockIdx.x;
    float (*wq)[CQ]        = (float(*)[CQ])smem;
    float (*wk)[CKV]       = (float(*)[CKV])(smem + 8192);
    float (*redq)[64][17]  = (float(*)[64][17])(smem + 12288);
    float (*redk)[64][17]  = (float(*)[64][17])(smem + 29696);
    for (int i = t; i < QDIM * CQ; i += 256) wq[i >> 7][i & 127] = Wq[i];
    for (int i = t; i < QDIM * CKV; i += 256) wk[i >> 6][i & 63] = Wk[i];
    __syncthreads();
    int b = bid >> 6;
    int n0 = (bid & 63) << 6;
    int px = t & 63, cg = t >> 6;
    int n = n0 + px;
    const float* xqp = xq + (size_t)b * CQ * NPIX + n;
    const float* xkp = xkv + (size_t)b * CKV * NPIX + n;
    float qa[QDIM], ka[QDIM];
    #pragma unroll
    for (int d = 0; d < QDIM; d++) { qa[d] = 0.f; ka[d] = 0.f; }
    int cq0 = cg * 32, ck0 = cg * 16;
    #pragma unroll 4
    for (int c = cq0; c < cq0 + 32; c++) {
      float x = xqp[(size_t)c * NPIX];
      #pragma unroll
      for (int d = 0; d < QDIM; d++) qa[d] = fmaf(wq[d][c], x, qa[d]);
    }
    #pragma unroll 4
    for (int c = ck0; c < ck0 + 16; c++) {
      float x = xkp[(size_t)c * NPIX];
      #pragma unroll
      for (int d = 0; d < QDIM; d++) ka[d] = fmaf(wk[d][c], x, ka[d]);
    }
    #pragma unroll
    for (int d = 0; d < QDIM; d++) { redq[cg][px][d] = qa[d]; redk[cg][px][d] = ka[d]; }
    __syncthreads();
    const float SC = 0.25f * 1.44269504088896340736f;  // dim^-0.5 * log2(e)
    int d0 = cg * 4;
    u16x4 oq, ok;
    #pragma unroll
    for (int j = 0; j < 4; j++) {
      float sq = redq[0][px][d0 + j] + redq[1][px][d0 + j]
               + redq[2][px][d0 + j] + redq[3][px][d0 + j] + bq[d0 + j];
      oq[j] = f2bf(sq * SC);
      float sk = redk[0][px][d0 + j] + redk[1][px][d0 + j]
               + redk[2][px][d0 + j] + redk[3][px][d0 + j] + bk[d0 + j];
      ok[j] = f2bf(sk);
    }
    size_t o = ((size_t)b * NPIX + n) * QDIM + d0;
    *(u16x4*)(Qs + o) = oq;
    *(u16x4*)(Ks + o) = ok;
  } else {
    int bid = (int)blockIdx.x - NB * 64;
    float (*wv)[CKV + 1] = (float(*)[CKV + 1])smem;
    float (*xs)[64 + 4]  = (float(*)[64 + 4])(smem + 33280);
    int b = bid >> 6;
    int n0 = (bid & 63) << 6;
    for (int i = t; i < CQ * CKV; i += 256) wv[i >> 6][i & 63] = Wv[i];
    const float* xp = xkv + (size_t)b * CKV * NPIX + n0;
    for (int i = t; i < CKV * 16; i += 256) {
      int c = i >> 4, c4 = (i & 15) * 4;
      *(f32x4*)(&xs[c][c4]) = *(const f32x4*)(xp + (size_t)c * NPIX + c4);
    }
    __syncthreads();
    int cog = t >> 4, pg = t & 15;
    int co0 = cog * 8, p0 = pg * 4;
    float acc[8][4];
    #pragma unroll
    for (int j = 0; j < 8; j++) {
      float bb = bv[co0 + j];
      #pragma unroll
      for (int p = 0; p < 4; p++) acc[j][p] = bb;
    }
    #pragma unroll 2
    for (int c = 0; c < CKV; c++) {
      float xv[4];
      #pragma unroll
      for (int p = 0; p < 4; p++) xv[p] = xs[c][p0 + p];
      #pragma unroll
      for (int j = 0; j < 8; j++) {
        float wvv = wv[co0 + j][c];
        #pragma unroll
        for (int p = 0; p < 4; p++) acc[j][p] = fmaf(wvv, xv[p], acc[j][p]);
      }
    }
    #pragma unroll
    for (int j = 0; j < 8; j++) {
      u16x4 ov;
      #pragma unroll
      for (int p = 0; p < 4; p++) ov[p] = f2bf(acc[j][p]);
      *(u16x4*)(Vt + ((size_t)b * CQ + co0 + j) * NPIX + n0 + p0) = ov;
    }
  }
}

// ---- flash attention + fused Wo projection + residual; 256-key tiles, hoisted reads ----
// 512 thr = 8 waves = 2 q-pairs (p) x 4 key-phases (ph, 64 keys each). 16 iterations,
// 1 barrier each (half of r14). 128 KB LDS -> 1 block/CU -> (512,2) = 256-reg cap, which
// finally allows hoisting all 16 PV ds_read_b128 to the iteration top (no spill).
__global__ __launch_bounds__(512, 2) void attn(
    const u16* __restrict__ Qs, const u16* __restrict__ Ks, const u16* __restrict__ Vt,
    const float* __restrict__ Wo, const float* __restrict__ bo,
    const float* __restrict__ gamma, const float* __restrict__ xq,
    float* __restrict__ out)
{
  __shared__ u16 v_s[2][128][256];   // 128 KB; loop tiles, then merge (64 KB) + O staging
  __shared__ float d_red[2][2][32];  // [pair][slot][q]
  __shared__ float d_inv[2][32];
  __shared__ float bos[128];

  int t = (int)threadIdx.x;
  int w = t >> 6, l = t & 63, l31 = l & 31, hi = l >> 5;
  int p = w >> 2, ph = w & 3;
  int sw = ((int)blockIdx.x & 7) * 64 + ((int)blockIdx.x >> 3);  // 1 batch per XCD
  int b = sw >> 6, q0 = (sw & 63) * 64;

  const u16* Qb = Qs + (size_t)b * NPIX * QDIM;
  const u16* Kb = Ks + (size_t)b * NPIX * QDIM;
  const u16* Vb = Vt + (size_t)b * CQ * NPIX;

  if (t < 128) bos[t] = bo[t];   // covered by first loop barrier

  // Q B-frag: col q = l31, k(d) = hi*8+e (resident all kernel)
  bf16x8 qf = *(const bf16x8*)(Qb + (size_t)(q0 + p * 32 + l31) * QDIM + hi * 8);

  // DMA staging: wave w rows w*16..+16 via 8 insts; inst j: row = w*16 + 2j + (l>>5),
  // phys chunk l&31 sources logical chunk (l&31) ^ (row&15) = (l&31) ^ (2j + (l>>5)).
  int l5 = l >> 5, c32 = l & 31;
  const u16* kp = Kb + (size_t)(ph * 64 + l31) * QDIM + hi * 8;   // +32*QDIM for sub1
  int rsw = l31 & 15;                            // read-side row XOR component

  f32x16 acc[4];
  #pragma unroll
  for (int cb = 0; cb < 4; cb++)
    #pragma unroll
    for (int r = 0; r < 16; r++) acc[cb][r] = 0.f;
  float lsum = 0.f;

  f32x16 z;
  #pragma unroll
  for (int r = 0; r < 16; r++) z[r] = 0.f;

  auto PACK = [&](const f32x16& s, u32x4* aw) {   // 16 exp2 -> 2 A-frag words + lsum
    float pv[16];
    #pragma unroll
    for (int r = 0; r < 16; r++) {
      pv[r] = __builtin_amdgcn_exp2f(s[r]);
      lsum += pv[r];
    }
    u32 a0 = cvtpk(pv[0], pv[1]),  b0 = cvtpk(pv[2], pv[3]);
    u32 c0 = cvtpk(pv[4], pv[5]),  d0 = cvtpk(pv[6], pv[7]);
    plswap(a0, c0); plswap(b0, d0);
    aw[0] = u32x4{a0, b0, c0, d0};
    u32 a1 = cvtpk(pv[8], pv[9]),  b1 = cvtpk(pv[10], pv[11]);
    u32 c1 = cvtpk(pv[12], pv[13]), d1 = cvtpk(pv[14], pv[15]);
    plswap(a1, c1); plswap(b1, d1);
    aw[1] = u32x4{a1, b1, c1, d1};
  };

  // prologue: DMA tile 0 -> buf0 (drained by iter-0 barrier); preload K tiles 0,1
  #pragma unroll
  for (int j = 0; j < 8; j++)
    gload_lds16(Vb + (size_t)(w * 16 + 2 * j + l5) * NPIX + (c32 ^ (2 * j + l5)) * 8,
                &v_s[0][w * 16 + 2 * j][0]);
  bf16x8 kcA = *(const bf16x8*)(kp);
  bf16x8 kcB = *(const bf16x8*)(kp + 32 * QDIM);
  bf16x8 knA = *(const bf16x8*)(kp + (size_t)KVBLK * QDIM);
  bf16x8 knB = *(const bf16x8*)(kp + (size_t)KVBLK * QDIM + 32 * QDIM);

  #pragma unroll 1
  for (int it = 0; it < NTI; it++) {
    __syncthreads();   // drains DMA for tile it; all reads of buf[(it+1)&1] (tile it-1) done

    if (it + 1 < NTI) { // async-stage tile it+1 into the freed buffer
      #pragma unroll
      for (int j = 0; j < 8; j++)
        gload_lds16(Vb + (size_t)(w * 16 + 2 * j + l5) * NPIX + (c32 ^ (2 * j + l5)) * 8
                       + (size_t)(it + 1) * KVBLK,
                    &v_s[(it + 1) & 1][w * 16 + 2 * j][0]);
    }

    // hoisted PV V-fragment reads for tile it: LDS pipe busy from cycle 0
    const u16 (*vs)[256] = v_s[it & 1];
    bf16x8 vf[16];
    #pragma unroll
    for (int c = 0; c < 4; c++)
      #pragma unroll
      for (int cb = 0; cb < 4; cb++)
        vf[c * 4 + cb] =
            *(const bf16x8*)(&vs[cb * 32 + l31][((ph * 8 + c * 2 + hi) ^ rsw) * 8]);

    // S^T = K Q for this wave's 64 keys (2 sub-chunks) x its pair's 32 q
    f32x16 s0 = __builtin_amdgcn_mfma_f32_32x32x16_bf16(kcA, qf, z, 0, 0, 0);
    f32x16 s1 = __builtin_amdgcn_mfma_f32_32x32x16_bf16(kcB, qf, z, 0, 0, 0);
    kcA = knA; kcB = knB;
    if (it + 2 < NTI) {
      knA = *(const bf16x8*)(kp + (size_t)(it + 2) * KVBLK * QDIM);
      knB = *(const bf16x8*)(kp + (size_t)(it + 2) * KVBLK * QDIM + 32 * QDIM);
    }

    u32x4 afw[4];
    PACK(s0, &afw[0]);
    PACK(s1, &afw[2]);

    #pragma unroll
    for (int c = 0; c < 4; c++) {
      bf16x8 af = __builtin_bit_cast(bf16x8, afw[c]);
      #pragma unroll
      for (int cb = 0; cb < 4; cb++)
        acc[cb] = __builtin_amdgcn_mfma_f32_32x32x16_bf16(af, vf[c * 4 + cb], acc[cb], 0, 0, 0);
    }
  }

  // ---- 2-step merge tree per q-pair: ph{2,3} -> ph{0,1}, then ph1 -> ph0 ----
  float tot = lsum + __shfl_xor(lsum, 32);
  __syncthreads();
  float* red = (float*)v_s;   // [2 pairs][2 slots][32 q][128 ch] f32 = 65536 B (fits)
  if (ph >= 2) {
    if (hi == 0) d_red[p][ph - 2][l31] = tot;
    float* dst = red + (((size_t)p * 2 + (ph - 2)) * 32) * 128;
    #pragma unroll
    for (int cb = 0; cb < 4; cb++)
      #pragma unroll
      for (int r = 0; r < 16; r++) {
        int row = (r & 3) + 8 * (r >> 2) + 4 * hi;
        dst[(size_t)row * 128 + cb * 32 + l31] = acc[cb][r];
      }
  }
  __syncthreads();
  if (ph < 2) {
    tot += d_red[p][ph][l31];
    const float* src = red + (((size_t)p * 2 + ph) * 32) * 128;
    #pragma unroll
    for (int cb = 0; cb < 4; cb++)
      #pragma unroll
      for (int r = 0; r < 16; r++) {
        int row = (r & 3) + 8 * (r >> 2) + 4 * hi;
        acc[cb][r] += src[(size_t)row * 128 + cb * 32 + l31];
      }
  }
  __syncthreads();
  if (ph == 1) {
    if (hi == 0) d_red[p][0][l31] = tot;
    float* dst = red + ((size_t)p * 2 * 32) * 128;
    #pragma unroll
    for (int cb = 0; cb < 4; cb++)
      #pragma unroll
      for (int r = 0; r < 16; r++) {
        int row = (r & 3) + 8 * (r >> 2) + 4 * hi;
        dst[(size_t)row * 128 + cb * 32 + l31] = acc[cb][r];
      }
  }
  __syncthreads();
  if (ph == 0) {
    tot += d_red[p][0][l31];
    if (hi == 0) d_inv[p][l31] = 1.0f / tot;
    const float* src = red + ((size_t)p * 2 * 32) * 128;
    #pragma unroll
    for (int cb = 0; cb < 4; cb++)
      #pragma unroll
      for (int r = 0; r < 16; r++) {
        int row = (r & 3) + 8 * (r >> 2) + 4 * hi;
        acc[cb][r] += src[(size_t)row * 128 + cb * 32 + l31];
      }
  }
  __syncthreads();   // red reads done; d_inv visible
  // ---- normalized bf16 O -> LDS [64][128], XOR chunk swizzle (first 16 KB of v_s) ----
  u16* Old = (u16*)v_s;
  if (ph == 0) {
    #pragma unroll
    for (int cb = 0; cb < 4; cb++)
      #pragma unroll
      for (int r = 0; r < 16; r++) {
        int row = (r & 3) + 8 * (r >> 2) + 4 * hi;
        int q = p * 32 + row;
        int c = cb * 32 + l31;
        Old[q * 128 + (((c >> 3) ^ (row & 15)) << 3) + (c & 7)] =
            f2bf(acc[cb][r] * d_inv[p][row]);
      }
  }
  __syncthreads();
  // ---- Wo A-frags loaded LATE (short live range; no epilogue spill) ----
  int g2 = w >> 1, qh = w & 1;   // wave -> 32 out-ch group, 32-q half
  bf16x8 woF[8];
  {
    const float* wrow = Wo + (size_t)(g2 * 32 + l31) * CQ + hi * 8;
    #pragma unroll
    for (int kc8 = 0; kc8 < 8; kc8++) {
      f32x4 a = *(const f32x4*)(wrow + kc8 * 16);
      f32x4 c4 = *(const f32x4*)(wrow + kc8 * 16 + 4);
      u32x4 pk = { cvtpk(a[0], a[1]), cvtpk(a[2], a[3]),
                   cvtpk(c4[0], c4[1]), cvtpk(c4[2], c4[3]) };
      woF[kc8] = __builtin_bit_cast(bf16x8, pk);
    }
  }
  // ---- Wo GEMM: wave -> 32 out-ch x 32 q; D rows = o, cols = q ----
  float g = gamma[0];
  const float* xb = xq + (size_t)b * CQ * NPIX;
  float* ob = out + (size_t)b * CQ * NPIX;
  f32x16 e = z;
  int q = qh * 32 + l31;
  #pragma unroll
  for (int kc8 = 0; kc8 < 8; kc8++) {
    int phys = (kc8 * 2 + hi) ^ (l31 & 15);
    bf16x8 of = *(const bf16x8*)(Old + q * 128 + phys * 8);
    e = __builtin_amdgcn_mfma_f32_32x32x16_bf16(woF[kc8], of, e, 0, 0, 0);
  }
  #pragma unroll
  for (int r = 0; r < 16; r++) {
    int o = g2 * 32 + (r & 3) + 8 * (r >> 2) + 4 * hi;
    size_t idx = (size_t)o * NPIX + q0 + qh * 32 + l31;
    ob[idx] = g * (e[r] + bos[o]) + xb[idx];
  }
}

extern "C" void kernel_launch(void* const* d_in, const int* in_sizes, int n_in,
                              void* d_out, int out_size, void* d_ws, size_t ws_size,
                              hipStream_t stream) {
  const float* x4q  = (const float*)d_in[0];
  const float* x4kv = (const float*)d_in[1];
  const float* Wq   = (const float*)d_in[2];
  const float* bq   = (const float*)d_in[3];
  const float* Wk   = (const float*)d_in[4];
  const float* bk   = (const float*)d_in[5];
  const float* Wv   = (const float*)d_in[6];
  const float* bv   = (const float*)d_in[7];
  const float* Wo   = (const float*)d_in[8];
  const float* bo   = (const float*)d_in[9];
  const float* gamma = (const float*)d_in[10];
  float* out = (float*)d_out;

  u16* Qs = (u16*)d_ws;                               // 1 MB
  u16* Ks = Qs + (size_t)NB * NPIX * QDIM;            // 1 MB
  u16* Vt = Ks + (size_t)NB * NPIX * QDIM;            // 8 MB

  proj_qkv<<<dim3(NB * 128), dim3(256), 0, stream>>>(x4q, Wq, bq, x4kv, Wk, bk,
                                                     Wv, bv, Qs, Ks, Vt);
  attn<<<dim3(NB * 64), dim3(512), 0, stream>>>(Qs, Ks, Vt, Wo, bo, gamma, x4q, out);
}

// Round 16
// 74.602 us; speedup vs baseline: 1.2373x; 1.2373x over previous
//
#include <hip/hip_runtime.h>

#define NB 8
#define CQ 128
#define CKV 64
#define NPIX 4096
#define QDIM 16
#define KVBLK 128
#define NTI (NPIX / KVBLK)   // 32 tiles of 128 keys

typedef float f32x4 __attribute__((ext_vector_type(4)));
typedef float f32x16 __attribute__((ext_vector_type(16)));
typedef __bf16 bf16x8 __attribute__((ext_vector_type(8)));
typedef unsigned short u16;
typedef u16 u16x4 __attribute__((ext_vector_type(4)));
typedef unsigned int u32;
typedef u32 u32x2 __attribute__((ext_vector_type(2)));
typedef u32 u32x4 __attribute__((ext_vector_type(4)));

static __device__ __forceinline__ u16 f2bf(float f) {
  unsigned int u = __builtin_bit_cast(unsigned int, f);
  u = (u + 0x7FFFu + ((u >> 16) & 1u)) >> 16;
  return (u16)u;
}
static __device__ __forceinline__ u32 cvtpk(float lo, float hi) {
  u32 r; asm("v_cvt_pk_bf16_f32 %0, %1, %2" : "=v"(r) : "v"(lo), "v"(hi)); return r;
}
static __device__ __forceinline__ void plswap(u32& a, u32& b) {
#if __has_builtin(__builtin_amdgcn_permlane32_swap)
  u32x2 r = __builtin_amdgcn_permlane32_swap(a, b, false, false);
  a = r[0]; b = r[1];
#else
  asm volatile("v_permlane32_swap_b32 %0, %1" : "+v"(a), "+v"(b));
#endif
}
// async global->LDS, 16B per lane; LDS dest = uniform base + lane*16 (per-lane global src)
static __device__ __forceinline__ void gload_lds16(const void* g, void* l) {
  __builtin_amdgcn_global_load_lds((const __attribute__((address_space(1))) void*)g,
                                   (__attribute__((address_space(3))) void*)l, 16, 0, 0);
}

// ---- merged q,k,v projections: blocks [0,512) do q/k; blocks [512,768) do v via MFMA ----
// qk path: 4-way channel split per wave, LDS reduce -> Qs/Ks [B][N][16] bf16 (Q pre-scaled).
// v path:  128px/block MFMA GEMM (Wv A-frags from L2, x staged bf16 in LDS) -> Vt [B][128][N].
__global__ __launch_bounds__(256) void proj_qkv(
    const float* __restrict__ xq, const float* __restrict__ Wq, const float* __restrict__ bq,
    const float* __restrict__ xkv, const float* __restrict__ Wk, const float* __restrict__ bk,
    const float* __restrict__ Wv, const float* __restrict__ bv,
    u16* __restrict__ Qs, u16* __restrict__ Ks, u16* __restrict__ Vt)
{
  __shared__ __align__(16) char smem[50688];
  int t = threadIdx.x;
  if ((int)blockIdx.x < NB * 64) {
    int bid = (int)blockIdx.x;
    float (*wq)[CQ]        = (float(*)[CQ])smem;
    float (*wk)[CKV]       = (float(*)[CKV])(smem + 8192);
    float (*redq)[64][17]  = (float(*)[64][17])(smem + 12288);
    float (*redk)[64][17]  = (float(*)[64][17])(smem + 29696);
    for (int i = t; i < QDIM * CQ; i += 256) wq[i >> 7][i & 127] = Wq[i];
    for (int i = t; i < QDIM * CKV; i += 256) wk[i >> 6][i & 63] = Wk[i];
    __syncthreads();
    int b = bid >> 6;
    int n0 = (bid & 63) << 6;
    int px = t & 63, cg = t >> 6;
    int n = n0 + px;
    const float* xqp = xq + (size_t)b * CQ * NPIX + n;
    const float* xkp = xkv + (size_t)b * CKV * NPIX + n;
    float qa[QDIM], ka[QDIM];
    #pragma unroll
    for (int d = 0; d < QDIM; d++) { qa[d] = 0.f; ka[d] = 0.f; }
    int cq0 = cg * 32, ck0 = cg * 16;
    #pragma unroll 4
    for (int c = cq0; c < cq0 + 32; c++) {
      float x = xqp[(size_t)c * NPIX];
      #pragma unroll
      for (int d = 0; d < QDIM; d++) qa[d] = fmaf(wq[d][c], x, qa[d]);
    }
    #pragma unroll 4
    for (int c = ck0; c < ck0 + 16; c++) {
      float x = xkp[(size_t)c * NPIX];
      #pragma unroll
      for (int d = 0; d < QDIM; d++) ka[d] = fmaf(wk[d][c], x, ka[d]);
    }
    #pragma unroll
    for (int d = 0; d < QDIM; d++) { redq[cg][px][d] = qa[d]; redk[cg][px][d] = ka[d]; }
    __syncthreads();
    const float SC = 0.25f * 1.44269504088896340736f;  // dim^-0.5 * log2(e)
    int d0 = cg * 4;
    u16x4 oq, ok;
    #pragma unroll
    for (int j = 0; j < 4; j++) {
      float sq = redq[0][px][d0 + j] + redq[1][px][d0 + j]
               + redq[2][px][d0 + j] + redq[3][px][d0 + j] + bq[d0 + j];
      oq[j] = f2bf(sq * SC);
      float sk = redk[0][px][d0 + j] + redk[1][px][d0 + j]
               + redk[2][px][d0 + j] + redk[3][px][d0 + j] + bk[d0 + j];
      ok[j] = f2bf(sk);
    }
    size_t o = ((size_t)b * NPIX + n) * QDIM + d0;
    *(u16x4*)(Qs + o) = oq;
    *(u16x4*)(Ks + o) = ok;
  } else {
    // ---- v path: 256 blocks, 128 px each; Vt[co][px] = Wv x + bv via 32x32x16 MFMA ----
    int bid = (int)blockIdx.x - NB * 64;
    u16 (*xs)[72] = (u16(*)[72])smem;          // [128 px][72 c] bf16; 144B rows, 16B aligned
    float* bvs = (float*)(smem + 128 * 72 * 2);
    int b = bid >> 5;
    int n0 = (bid & 31) << 7;
    int w = t >> 6, l = t & 63, l31 = l & 31, hi = l >> 5;
    if (t < 128) bvs[t] = bv[t];
    const float* xp = xkv + (size_t)b * CKV * NPIX + n0;
    // stage x transposed [px][c] as bf16 (scalar coalesced loads, 8B LDS writes)
    for (int i = t; i < 128 * 16; i += 256) {
      int px = i & 127, c4 = (i >> 7) * 4;
      float v0 = xp[(size_t)(c4 + 0) * NPIX + px];
      float v1 = xp[(size_t)(c4 + 1) * NPIX + px];
      float v2 = xp[(size_t)(c4 + 2) * NPIX + px];
      float v3 = xp[(size_t)(c4 + 3) * NPIX + px];
      u32x2 pk = { cvtpk(v0, v1), cvtpk(v2, v3) };
      *(u32x2*)(&xs[px][c4]) = pk;
    }
    // Wv A-frags: row co = w*32+l31, k = kk*16 + hi*8 + e (from L2, tiny)
    bf16x8 wvF[4];
    {
      const float* wrow = Wv + (size_t)(w * 32 + l31) * CKV + hi * 8;
      #pragma unroll
      for (int kk = 0; kk < 4; kk++) {
        f32x4 a = *(const f32x4*)(wrow + kk * 16);
        f32x4 c4 = *(const f32x4*)(wrow + kk * 16 + 4);
        u32x4 pk = { cvtpk(a[0], a[1]), cvtpk(a[2], a[3]),
                     cvtpk(c4[0], c4[1]), cvtpk(c4[2], c4[3]) };
        wvF[kk] = __builtin_bit_cast(bf16x8, pk);
      }
    }
    __syncthreads();
    f32x16 z;
    #pragma unroll
    for (int r = 0; r < 16; r++) z[r] = 0.f;
    u16* vout = Vt + ((size_t)b * CQ + w * 32) * NPIX + n0;
    #pragma unroll
    for (int n2 = 0; n2 < 4; n2++) {
      f32x16 acc = z;
      #pragma unroll
      for (int kk = 0; kk < 4; kk++) {
        bf16x8 xf = *(const bf16x8*)(&xs[n2 * 32 + l31][kk * 16 + hi * 8]);
        acc = __builtin_amdgcn_mfma_f32_32x32x16_bf16(wvF[kk], xf, acc, 0, 0, 0);
      }
      #pragma unroll
      for (int r = 0; r < 16; r++) {
        int row = (r & 3) + 8 * (r >> 2) + 4 * hi;   // local co
        vout[(size_t)row * NPIX + n2 * 32 + l31] = f2bf(acc[r] + bvs[w * 32 + row]);
      }
    }
  }
}

// ---- flash attention + fused Wo projection + residual (round-13 configuration) ----
// Loop = fat-wave (4 waves = 4 key-phases, each wave all 64 q rows, shared V-fragment
// reads, DMA staging, 1 barrier/tile). Epilogue = 2-step merge -> q-half split -> bf16 O
// in LDS -> woF loaded LATE -> Wo GEMM + residual.
__global__ __launch_bounds__(256, 2) void attn(
    const u16* __restrict__ Qs, const u16* __restrict__ Ks, const u16* __restrict__ Vt,
    const float* __restrict__ Wo, const float* __restrict__ bo,
    const float* __restrict__ gamma, const float* __restrict__ xq,
    float* __restrict__ out)
{
  __shared__ u16 v_s[2][128][128];   // 64 KB; loop tiles, then merge/O-staging scratch
  __shared__ float d_red[2][2][32];  // step-1 denom slots [slot][pair][q]
  __shared__ float d_x[2][32];       // step-2 cross-pair denom exchange
  __shared__ float d_inv[2][32];     // final 1/denom [pair][q]
  __shared__ float bos[128];

  int t = (int)threadIdx.x;
  int w = t >> 6, l = t & 63, l31 = l & 31, hi = l >> 5;
  int ph = w;                        // 4 waves = 4 key phases
  int sw = ((int)blockIdx.x & 7) * 64 + ((int)blockIdx.x >> 3);  // 1 batch per XCD
  int b = sw >> 6, q0 = (sw & 63) * 64;

  const u16* Qb = Qs + (size_t)b * NPIX * QDIM;
  const u16* Kb = Ks + (size_t)b * NPIX * QDIM;
  const u16* Vb = Vt + (size_t)b * CQ * NPIX;

  if (t < 128) bos[t] = bo[t];   // covered by first loop barrier

  // Q B-frags for both pairs: col q = l31 (+32), k(d) = hi*8+e
  bf16x8 qf0 = *(const bf16x8*)(Qb + (size_t)(q0 + l31) * QDIM + hi * 8);
  bf16x8 qf1 = *(const bf16x8*)(Qb + (size_t)(q0 + 32 + l31) * QDIM + hi * 8);

  // DMA staging: wave w rows w*32..+32 via 8 insts; inst j rows w*32+j*4+(l>>4);
  // phys chunk l&15 sources logical chunk (l&15)^(row&15) = lx ^ ((j&3)<<2).
  int row0 = w * 32 + (l >> 4);
  int lx = (l & 15) ^ (l >> 4);
  const u16* kp = Kb + (size_t)(ph * 32 + l31) * QDIM + hi * 8;
  int rsw = l31 & 15;                            // read-side row XOR component

  f32x16 acc0[4], acc1[4];
  #pragma unroll
  for (int cb = 0; cb < 4; cb++)
    #pragma unroll
    for (int r = 0; r < 16; r++) { acc0[cb][r] = 0.f; acc1[cb][r] = 0.f; }
  float lsum0 = 0.f, lsum1 = 0.f;

  u32x4 afw0[2], afw1[2];

  auto PACK = [&](const f32x16& s, u32x4* aw, float& ls) {
    float pv[16];
    #pragma unroll
    for (int r = 0; r < 16; r++) {
      pv[r] = __builtin_amdgcn_exp2f(s[r]);
      ls += pv[r];
    }
    u32 a0 = cvtpk(pv[0], pv[1]),  b0 = cvtpk(pv[2], pv[3]);
    u32 c0 = cvtpk(pv[4], pv[5]),  d0 = cvtpk(pv[6], pv[7]);
    plswap(a0, c0); plswap(b0, d0);
    aw[0] = u32x4{a0, b0, c0, d0};
    u32 a1 = cvtpk(pv[8], pv[9]),  b1 = cvtpk(pv[10], pv[11]);
    u32 c1 = cvtpk(pv[12], pv[13]), d1 = cvtpk(pv[14], pv[15]);
    plswap(a1, c1); plswap(b1, d1);
    aw[1] = u32x4{a1, b1, c1, d1};
  };

  f32x16 z;
  #pragma unroll
  for (int r = 0; r < 16; r++) z[r] = 0.f;

  // prologue: DMA tile 0 -> buf0; preload K tiles 0,1
  #pragma unroll
  for (int j = 0; j < 8; j++)
    gload_lds16(Vb + (size_t)(row0 + j * 4) * NPIX + (lx ^ ((j & 3) << 2)) * 8,
                &v_s[0][w * 32 + j * 4][0]);
  bf16x8 kc = *(const bf16x8*)(kp);
  bf16x8 kn = *(const bf16x8*)(kp + (size_t)KVBLK * QDIM);

  #pragma unroll 1
  for (int it = 0; it < NTI; it++) {
    __syncthreads();   // drains DMA for tile it; all reads of buf[(it+1)&1] (tile it-1) done

    if (it + 1 < NTI) { // async-stage tile it+1 into the freed buffer
      #pragma unroll
      for (int j = 0; j < 8; j++)
        gload_lds16(Vb + (size_t)(row0 + j * 4) * NPIX + (lx ^ ((j & 3) << 2)) * 8
                       + (size_t)(it + 1) * KVBLK,
                    &v_s[(it + 1) & 1][w * 32 + j * 4][0]);
    }

    // S^T = K Q for this wave's 32 keys, both q-pairs (K-frag shared)
    f32x16 s0 = __builtin_amdgcn_mfma_f32_32x32x16_bf16(kc, qf0, z, 0, 0, 0);
    f32x16 s1 = __builtin_amdgcn_mfma_f32_32x32x16_bf16(kc, qf1, z, 0, 0, 0);
    kc = kn;
    if (it + 2 < NTI) kn = *(const bf16x8*)(kp + (size_t)(it + 2) * KVBLK * QDIM);
    PACK(s0, afw0, lsum0);
    PACK(s1, afw1, lsum1);

    // PV: each V fragment read ONCE, feeds both pairs
    const u16 (*vs)[128] = v_s[it & 1];
    #pragma unroll
    for (int c = 0; c < 2; c++) {
      bf16x8 af0 = __builtin_bit_cast(bf16x8, afw0[c]);
      bf16x8 af1 = __builtin_bit_cast(bf16x8, afw1[c]);
      #pragma unroll
      for (int cb = 0; cb < 4; cb++) {
        int chunk = (ph * 4 + c * 2 + hi) ^ rsw;
        bf16x8 vf = *(const bf16x8*)(&vs[cb * 32 + l31][chunk * 8]);
        acc0[cb] = __builtin_amdgcn_mfma_f32_32x32x16_bf16(af0, vf, acc0[cb], 0, 0, 0);
        acc1[cb] = __builtin_amdgcn_mfma_f32_32x32x16_bf16(af1, vf, acc1[cb], 0, 0, 0);
      }
    }
  }

  float tot0 = lsum0 + __shfl_xor(lsum0, 32);
  float tot1 = lsum1 + __shfl_xor(lsum1, 32);

  // ---- merge step 1: ph{2,3} -> ph{0,1} (full 64q x 128c, f32 via v_s) ----
  __syncthreads();
  float* red = (float*)v_s;   // 16384 f32: slot0 = [0,8192), slot1 = [8192,16384)
  if (ph >= 2) {
    if (hi == 0) { d_red[ph - 2][0][l31] = tot0; d_red[ph - 2][1][l31] = tot1; }
    float* dst = red + (size_t)(ph - 2) * 64 * 128;
    #pragma unroll
    for (int cb = 0; cb < 4; cb++)
      #pragma unroll
      for (int r = 0; r < 16; r++) {
        int row = (r & 3) + 8 * (r >> 2) + 4 * hi;
        dst[(size_t)row * 128 + cb * 32 + l31] = acc0[cb][r];
        dst[(size_t)(row + 32) * 128 + cb * 32 + l31] = acc1[cb][r];
      }
  }
  __syncthreads();
  // ---- step-1 add + step-2 cross-pair exchange (ph0 keeps q 0-31, ph1 keeps q 32-63) ----
  if (ph < 2) {
    tot0 += d_red[ph][0][l31];
    tot1 += d_red[ph][1][l31];
    const float* src = red + (size_t)ph * 64 * 128;
    #pragma unroll
    for (int cb = 0; cb < 4; cb++)
      #pragma unroll
      for (int r = 0; r < 16; r++) {
        int row = (r & 3) + 8 * (r >> 2) + 4 * hi;
        acc0[cb][r] += src[(size_t)row * 128 + cb * 32 + l31];
        acc1[cb][r] += src[(size_t)(row + 32) * 128 + cb * 32 + l31];
      }
    if (ph == 0) {
      if (hi == 0) d_x[0][l31] = tot1;
      #pragma unroll
      for (int cb = 0; cb < 4; cb++)
        #pragma unroll
        for (int r = 0; r < 16; r++) {
          int row = (r & 3) + 8 * (r >> 2) + 4 * hi;
          red[(size_t)(row + 32) * 128 + cb * 32 + l31] = acc1[cb][r];  // slot0 rows 32-63
        }
    } else {
      if (hi == 0) d_x[1][l31] = tot0;
      #pragma unroll
      for (int cb = 0; cb < 4; cb++)
        #pragma unroll
        for (int r = 0; r < 16; r++) {
          int row = (r & 3) + 8 * (r >> 2) + 4 * hi;
          red[8192 + (size_t)row * 128 + cb * 32 + l31] = acc0[cb][r];  // slot1 rows 0-31
        }
    }
  }
  __syncthreads();
  if (ph == 0) {
    float denom = tot0 + d_x[1][l31];       // full denom for q = l31
    if (hi == 0) d_inv[0][l31] = 1.0f / denom;
    #pragma unroll
    for (int cb = 0; cb < 4; cb++)
      #pragma unroll
      for (int r = 0; r < 16; r++) {
        int row = (r & 3) + 8 * (r >> 2) + 4 * hi;
        acc0[cb][r] += red[8192 + (size_t)row * 128 + cb * 32 + l31];
      }
  } else if (ph == 1) {
    float denom = tot1 + d_x[0][l31];       // full denom for q = 32 + l31
    if (hi == 0) d_inv[1][l31] = 1.0f / denom;
    #pragma unroll
    for (int cb = 0; cb < 4; cb++)
      #pragma unroll
      for (int r = 0; r < 16; r++) {
        int row = (r & 3) + 8 * (r >> 2) + 4 * hi;
        acc1[cb][r] += red[(size_t)(row + 32) * 128 + cb * 32 + l31];
      }
  }
  __syncthreads();
  // ---- normalized bf16 O -> LDS [64][128] with XOR chunk swizzle (first 16 KB of v_s) ----
  u16* Old = (u16*)v_s;
  if (ph == 0) {
    #pragma unroll
    for (int cb = 0; cb < 4; cb++)
      #pragma unroll
      for (int r = 0; r < 16; r++) {
        int row = (r & 3) + 8 * (r >> 2) + 4 * hi;
        int c = cb * 32 + l31;
        Old[row * 128 + (((c >> 3) ^ (row & 15)) << 3) + (c & 7)] =
            f2bf(acc0[cb][r] * d_inv[0][row]);
      }
  } else if (ph == 1) {
    #pragma unroll
    for (int cb = 0; cb < 4; cb++)
      #pragma unroll
      for (int r = 0; r < 16; r++) {
        int q = 32 + (r & 3) + 8 * (r >> 2) + 4 * hi;
        int c = cb * 32 + l31;
        Old[q * 128 + (((c >> 3) ^ (q & 15)) << 3) + (c & 7)] =
            f2bf(acc1[cb][r] * d_inv[1][(q - 32)]);
      }
  }
  __syncthreads();
  // ---- Wo A-frags loaded LATE (short live range; no epilogue spill) ----
  bf16x8 woF[8];
  {
    const float* wrow = Wo + (size_t)(w * 32 + l31) * CQ + hi * 8;
    #pragma unroll
    for (int kc8 = 0; kc8 < 8; kc8++) {
      f32x4 a = *(const f32x4*)(wrow + kc8 * 16);
      f32x4 c4 = *(const f32x4*)(wrow + kc8 * 16 + 4);
      u32x4 pk = { cvtpk(a[0], a[1]), cvtpk(a[2], a[3]),
                   cvtpk(c4[0], c4[1]), cvtpk(c4[2], c4[3]) };
      woF[kc8] = __builtin_bit_cast(bf16x8, pk);
    }
  }
  // ---- Wo GEMM: wave w -> out channels w*32..+32, all 64 n; D rows = o, cols = q ----
  float g = gamma[0];
  const float* xb = xq + (size_t)b * CQ * NPIX;
  float* ob = out + (size_t)b * CQ * NPIX;
  #pragma unroll
  for (int qb = 0; qb < 2; qb++) {
    f32x16 e = z;
    int q = qb * 32 + l31;
    #pragma unroll
    for (int kc8 = 0; kc8 < 8; kc8++) {
      int phys = (kc8 * 2 + hi) ^ (l31 & 15);
      bf16x8 of = *(const bf16x8*)(Old + q * 128 + phys * 8);
      e = __builtin_amdgcn_mfma_f32_32x32x16_bf16(woF[kc8], of, e, 0, 0, 0);
    }
    #pragma unroll
    for (int r = 0; r < 16; r++) {
      int o = w * 32 + (r & 3) + 8 * (r >> 2) + 4 * hi;
      size_t idx = (size_t)o * NPIX + q0 + qb * 32 + l31;
      ob[idx] = g * (e[r] + bos[o]) + xb[idx];
    }
  }
}

extern "C" void kernel_launch(void* const* d_in, const int* in_sizes, int n_in,
                              void* d_out, int out_size, void* d_ws, size_t ws_size,
                              hipStream_t stream) {
  const float* x4q  = (const float*)d_in[0];
  const float* x4kv = (const float*)d_in[1];
  const float* Wq   = (const float*)d_in[2];
  const float* bq   = (const float*)d_in[3];
  const float* Wk   = (const float*)d_in[4];
  const float* bk   = (const float*)d_in[5];
  const float* Wv   = (const float*)d_in[6];
  const float* bv   = (const float*)d_in[7];
  const float* Wo   = (const float*)d_in[8];
  const float* bo   = (const float*)d_in[9];
  const float* gamma = (const float*)d_in[10];
  float* out = (float*)d_out;

  u16* Qs = (u16*)d_ws;                               // 1 MB
  u16* Ks = Qs + (size_t)NB * NPIX * QDIM;            // 1 MB
  u16* Vt = Ks + (size_t)NB * NPIX * QDIM;            // 8 MB

  proj_qkv<<<dim3(NB * 64 + NB * 32), dim3(256), 0, stream>>>(
      x4q, Wq, bq, x4kv, Wk, bk, Wv, bv, Qs, Ks, Vt);
  attn<<<dim3(NB * 64), dim3(256), 0, stream>>>(Qs, Ks, Vt, Wo, bo, gamma, x4q, out);
}

// Round 17
// 71.023 us; speedup vs baseline: 1.2996x; 1.0504x over previous
//
#include <hip/hip_runtime.h>

#define NB 8
#define CQ 128
#define CKV 64
#define NPIX 4096
#define QDIM 16
#define KVBLK 128
#define NTI (NPIX / KVBLK)   // 32 tiles of 128 keys

typedef float f32x4 __attribute__((ext_vector_type(4)));
typedef float f32x16 __attribute__((ext_vector_type(16)));
typedef __bf16 bf16x8 __attribute__((ext_vector_type(8)));
typedef unsigned short u16;
typedef u16 u16x4 __attribute__((ext_vector_type(4)));
typedef unsigned int u32;
typedef u32 u32x2 __attribute__((ext_vector_type(2)));
typedef u32 u32x4 __attribute__((ext_vector_type(4)));

static __device__ __forceinline__ u16 f2bf(float f) {
  unsigned int u = __builtin_bit_cast(unsigned int, f);
  u = (u + 0x7FFFu + ((u >> 16) & 1u)) >> 16;
  return (u16)u;
}
static __device__ __forceinline__ u32 cvtpk(float lo, float hi) {
  u32 r; asm("v_cvt_pk_bf16_f32 %0, %1, %2" : "=v"(r) : "v"(lo), "v"(hi)); return r;
}
static __device__ __forceinline__ void plswap(u32& a, u32& b) {
#if __has_builtin(__builtin_amdgcn_permlane32_swap)
  u32x2 r = __builtin_amdgcn_permlane32_swap(a, b, false, false);
  a = r[0]; b = r[1];
#else
  asm volatile("v_permlane32_swap_b32 %0, %1" : "+v"(a), "+v"(b));
#endif
}
// async global->LDS, 16B per lane; LDS dest = uniform base + lane*16 (per-lane global src)
static __device__ __forceinline__ void gload_lds16(const void* g, void* l) {
  __builtin_amdgcn_global_load_lds((const __attribute__((address_space(1))) void*)g,
                                   (__attribute__((address_space(3))) void*)l, 16, 0, 0);
}

// ---- unified q,k,v projections: 512 blocks x 64 px, all-MFMA ----
// Stage xq^T [64][136] and xkv^T [64][72] bf16 in LDS (xkv read ONCE, shared by K and V).
// Q: 4x mfma_16x16x32 per wave (A row=l&15, k=(l>>4)*8+e — round-0-verified layout).
// K: 2x. V: 8x mfma_32x32x16 (round-16-proven). Outputs: Qs/Ks [B][N][16], Vt [B][128][N].
__global__ __launch_bounds__(256) void proj_qkv(
    const float* __restrict__ xq, const float* __restrict__ Wq, const float* __restrict__ bq,
    const float* __restrict__ xkv, const float* __restrict__ Wk, const float* __restrict__ bk,
    const float* __restrict__ Wv, const float* __restrict__ bv,
    u16* __restrict__ Qs, u16* __restrict__ Ks, u16* __restrict__ Vt)
{
  __shared__ u16 xs_q[64][136];   // 17408 B; 272B rows, 16B aligned
  __shared__ u16 xs_k[64][72];    //  9216 B; 144B rows (r16-proven bank map)
  __shared__ float bvs[128];
  __shared__ float bqs[16], bks[16];

  int t = (int)threadIdx.x;
  int b = (int)blockIdx.x >> 6;
  int n0 = ((int)blockIdx.x & 63) << 6;   // 64 px per block
  int w = t >> 6, l = t & 63, l31 = l & 31, hi = l >> 5, l15 = l & 15, l4 = l >> 4;

  if (t < 128) bvs[t] = bv[t];
  else if (t < 144) bqs[t - 128] = bq[t - 128];
  else if (t < 160) bks[t - 144] = bk[t - 144];

  const float* xqp = xq + (size_t)b * CQ * NPIX + n0;
  const float* xkp = xkv + (size_t)b * CKV * NPIX + n0;
  // stage xq^T (64 px x 128 c) and xkv^T (64 px x 64 c) as bf16
  for (int i = t; i < 64 * 32; i += 256) {
    int px = i & 63, c4 = (i >> 6) * 4;
    float v0 = xqp[(size_t)(c4 + 0) * NPIX + px];
    float v1 = xqp[(size_t)(c4 + 1) * NPIX + px];
    float v2 = xqp[(size_t)(c4 + 2) * NPIX + px];
    float v3 = xqp[(size_t)(c4 + 3) * NPIX + px];
    u32x2 pk = { cvtpk(v0, v1), cvtpk(v2, v3) };
    *(u32x2*)(&xs_q[px][c4]) = pk;
  }
  for (int i = t; i < 64 * 16; i += 256) {
    int px = i & 63, c4 = (i >> 6) * 4;
    float v0 = xkp[(size_t)(c4 + 0) * NPIX + px];
    float v1 = xkp[(size_t)(c4 + 1) * NPIX + px];
    float v2 = xkp[(size_t)(c4 + 2) * NPIX + px];
    float v3 = xkp[(size_t)(c4 + 3) * NPIX + px];
    u32x2 pk = { cvtpk(v0, v1), cvtpk(v2, v3) };
    *(u32x2*)(&xs_k[px][c4]) = pk;
  }

  // weight A-frags (from L2, tiny). 16x16x32: row = l15, k = l4*8+e within each 32-chunk.
  bf16x8 wqF[4], wkF[2];
  #pragma unroll
  for (int j = 0; j < 4; j++) {
    const float* wr = Wq + (size_t)l15 * CQ + j * 32 + l4 * 8;
    f32x4 a = *(const f32x4*)(wr), c4 = *(const f32x4*)(wr + 4);
    u32x4 pk = { cvtpk(a[0], a[1]), cvtpk(a[2], a[3]),
                 cvtpk(c4[0], c4[1]), cvtpk(c4[2], c4[3]) };
    wqF[j] = __builtin_bit_cast(bf16x8, pk);
  }
  #pragma unroll
  for (int j = 0; j < 2; j++) {
    const float* wr = Wk + (size_t)l15 * CKV + j * 32 + l4 * 8;
    f32x4 a = *(const f32x4*)(wr), c4 = *(const f32x4*)(wr + 4);
    u32x4 pk = { cvtpk(a[0], a[1]), cvtpk(a[2], a[3]),
                 cvtpk(c4[0], c4[1]), cvtpk(c4[2], c4[3]) };
    wkF[j] = __builtin_bit_cast(bf16x8, pk);
  }
  // Wv A-frags (32x32x16): row = l31, k = hi*8+e within each 16-chunk; wave w rows w*32..+32
  bf16x8 wvF[4];
  {
    const float* wrow = Wv + (size_t)(w * 32 + l31) * CKV + hi * 8;
    #pragma unroll
    for (int kk = 0; kk < 4; kk++) {
      f32x4 a = *(const f32x4*)(wrow + kk * 16);
      f32x4 c4 = *(const f32x4*)(wrow + kk * 16 + 4);
      u32x4 pk = { cvtpk(a[0], a[1]), cvtpk(a[2], a[3]),
                   cvtpk(c4[0], c4[1]), cvtpk(c4[2], c4[3]) };
      wvF[kk] = __builtin_bit_cast(bf16x8, pk);
    }
  }
  __syncthreads();

  const float SC = 0.25f * 1.44269504088896340736f;  // dim^-0.5 * log2(e)
  f32x4 z4 = {0.f, 0.f, 0.f, 0.f};
  // ---- Q: wave w -> px w*16..+16; D col = px = l15, row d = l4*4 + r ----
  {
    f32x4 acc = z4;
    #pragma unroll
    for (int j = 0; j < 4; j++) {
      bf16x8 xf = *(const bf16x8*)(&xs_q[w * 16 + l15][j * 32 + l4 * 8]);
      acc = __builtin_amdgcn_mfma_f32_16x16x32_bf16(wqF[j], xf, acc, 0, 0, 0);
    }
    u16x4 oq;
    #pragma unroll
    for (int r = 0; r < 4; r++) oq[r] = f2bf((acc[r] + bqs[l4 * 4 + r]) * SC);
    *(u16x4*)(Qs + ((size_t)b * NPIX + n0 + w * 16 + l15) * QDIM + l4 * 4) = oq;
  }
  // ---- K: same structure, K-dim 64 ----
  {
    f32x4 acc = z4;
    #pragma unroll
    for (int j = 0; j < 2; j++) {
      bf16x8 xf = *(const bf16x8*)(&xs_k[w * 16 + l15][j * 32 + l4 * 8]);
      acc = __builtin_amdgcn_mfma_f32_16x16x32_bf16(wkF[j], xf, acc, 0, 0, 0);
    }
    u16x4 ok;
    #pragma unroll
    for (int r = 0; r < 4; r++) ok[r] = f2bf(acc[r] + bks[l4 * 4 + r]);
    *(u16x4*)(Ks + ((size_t)b * NPIX + n0 + w * 16 + l15) * QDIM + l4 * 4) = ok;
  }
  // ---- V: wave w -> out-ch w*32..+32, 2 px-groups of 32 ----
  {
    f32x16 z;
    #pragma unroll
    for (int r = 0; r < 16; r++) z[r] = 0.f;
    u16* vout = Vt + ((size_t)b * CQ + w * 32) * NPIX + n0;
    #pragma unroll
    for (int n2 = 0; n2 < 2; n2++) {
      f32x16 acc = z;
      #pragma unroll
      for (int kk = 0; kk < 4; kk++) {
        bf16x8 xf = *(const bf16x8*)(&xs_k[n2 * 32 + l31][kk * 16 + hi * 8]);
        acc = __builtin_amdgcn_mfma_f32_32x32x16_bf16(wvF[kk], xf, acc, 0, 0, 0);
      }
      #pragma unroll
      for (int r = 0; r < 16; r++) {
        int row = (r & 3) + 8 * (r >> 2) + 4 * hi;   // local co
        vout[(size_t)row * NPIX + n2 * 32 + l31] = f2bf(acc[r] + bvs[w * 32 + row]);
      }
    }
  }
}

// ---- flash attention + fused Wo projection + residual (round-13/16 configuration) ----
__global__ __launch_bounds__(256, 2) void attn(
    const u16* __restrict__ Qs, const u16* __restrict__ Ks, const u16* __restrict__ Vt,
    const float* __restrict__ Wo, const float* __restrict__ bo,
    const float* __restrict__ gamma, const float* __restrict__ xq,
    float* __restrict__ out)
{
  __shared__ u16 v_s[2][128][128];   // 64 KB; loop tiles, then merge/O-staging scratch
  __shared__ float d_red[2][2][32];  // step-1 denom slots [slot][pair][q]
  __shared__ float d_x[2][32];       // step-2 cross-pair denom exchange
  __shared__ float d_inv[2][32];     // final 1/denom [pair][q]
  __shared__ float bos[128];

  int t = (int)threadIdx.x;
  int w = t >> 6, l = t & 63, l31 = l & 31, hi = l >> 5;
  int ph = w;                        // 4 waves = 4 key phases
  int sw = ((int)blockIdx.x & 7) * 64 + ((int)blockIdx.x >> 3);  // 1 batch per XCD
  int b = sw >> 6, q0 = (sw & 63) * 64;

  const u16* Qb = Qs + (size_t)b * NPIX * QDIM;
  const u16* Kb = Ks + (size_t)b * NPIX * QDIM;
  const u16* Vb = Vt + (size_t)b * CQ * NPIX;

  if (t < 128) bos[t] = bo[t];   // covered by first loop barrier

  // Q B-frags for both pairs: col q = l31 (+32), k(d) = hi*8+e
  bf16x8 qf0 = *(const bf16x8*)(Qb + (size_t)(q0 + l31) * QDIM + hi * 8);
  bf16x8 qf1 = *(const bf16x8*)(Qb + (size_t)(q0 + 32 + l31) * QDIM + hi * 8);

  // DMA staging: wave w rows w*32..+32 via 8 insts; inst j rows w*32+j*4+(l>>4);
  // phys chunk l&15 sources logical chunk (l&15)^(row&15) = lx ^ ((j&3)<<2).
  int row0 = w * 32 + (l >> 4);
  int lx = (l & 15) ^ (l >> 4);
  const u16* kp = Kb + (size_t)(ph * 32 + l31) * QDIM + hi * 8;
  int rsw = l31 & 15;                            // read-side row XOR component

  f32x16 acc0[4], acc1[4];
  #pragma unroll
  for (int cb = 0; cb < 4; cb++)
    #pragma unroll
    for (int r = 0; r < 16; r++) { acc0[cb][r] = 0.f; acc1[cb][r] = 0.f; }
  float lsum0 = 0.f, lsum1 = 0.f;

  u32x4 afw0[2], afw1[2];

  auto PACK = [&](const f32x16& s, u32x4* aw, float& ls) {
    float pv[16];
    #pragma unroll
    for (int r = 0; r < 16; r++) {
      pv[r] = __builtin_amdgcn_exp2f(s[r]);
      ls += pv[r];
    }
    u32 a0 = cvtpk(pv[0], pv[1]),  b0 = cvtpk(pv[2], pv[3]);
    u32 c0 = cvtpk(pv[4], pv[5]),  d0 = cvtpk(pv[6], pv[7]);
    plswap(a0, c0); plswap(b0, d0);
    aw[0] = u32x4{a0, b0, c0, d0};
    u32 a1 = cvtpk(pv[8], pv[9]),  b1 = cvtpk(pv[10], pv[11]);
    u32 c1 = cvtpk(pv[12], pv[13]), d1 = cvtpk(pv[14], pv[15]);
    plswap(a1, c1); plswap(b1, d1);
    aw[1] = u32x4{a1, b1, c1, d1};
  };

  f32x16 z;
  #pragma unroll
  for (int r = 0; r < 16; r++) z[r] = 0.f;

  // prologue: DMA tile 0 -> buf0; preload K tiles 0,1
  #pragma unroll
  for (int j = 0; j < 8; j++)
    gload_lds16(Vb + (size_t)(row0 + j * 4) * NPIX + (lx ^ ((j & 3) << 2)) * 8,
                &v_s[0][w * 32 + j * 4][0]);
  bf16x8 kc = *(const bf16x8*)(kp);
  bf16x8 kn = *(const bf16x8*)(kp + (size_t)KVBLK * QDIM);

  #pragma unroll 1
  for (int it = 0; it < NTI; it++) {
    __syncthreads();   // drains DMA for tile it; all reads of buf[(it+1)&1] (tile it-1) done

    if (it + 1 < NTI) { // async-stage tile it+1 into the freed buffer
      #pragma unroll
      for (int j = 0; j < 8; j++)
        gload_lds16(Vb + (size_t)(row0 + j * 4) * NPIX + (lx ^ ((j & 3) << 2)) * 8
                       + (size_t)(it + 1) * KVBLK,
                    &v_s[(it + 1) & 1][w * 32 + j * 4][0]);
    }

    // S^T = K Q for this wave's 32 keys, both q-pairs (K-frag shared)
    f32x16 s0 = __builtin_amdgcn_mfma_f32_32x32x16_bf16(kc, qf0, z, 0, 0, 0);
    f32x16 s1 = __builtin_amdgcn_mfma_f32_32x32x16_bf16(kc, qf1, z, 0, 0, 0);
    kc = kn;
    if (it + 2 < NTI) kn = *(const bf16x8*)(kp + (size_t)(it + 2) * KVBLK * QDIM);
    PACK(s0, afw0, lsum0);
    PACK(s1, afw1, lsum1);

    // PV: each V fragment read ONCE, feeds both pairs
    const u16 (*vs)[128] = v_s[it & 1];
    #pragma unroll
    for (int c = 0; c < 2; c++) {
      bf16x8 af0 = __builtin_bit_cast(bf16x8, afw0[c]);
      bf16x8 af1 = __builtin_bit_cast(bf16x8, afw1[c]);
      #pragma unroll
      for (int cb = 0; cb < 4; cb++) {
        int chunk = (ph * 4 + c * 2 + hi) ^ rsw;
        bf16x8 vf = *(const bf16x8*)(&vs[cb * 32 + l31][chunk * 8]);
        acc0[cb] = __builtin_amdgcn_mfma_f32_32x32x16_bf16(af0, vf, acc0[cb], 0, 0, 0);
        acc1[cb] = __builtin_amdgcn_mfma_f32_32x32x16_bf16(af1, vf, acc1[cb], 0, 0, 0);
      }
    }
  }

  float tot0 = lsum0 + __shfl_xor(lsum0, 32);
  float tot1 = lsum1 + __shfl_xor(lsum1, 32);

  // ---- merge step 1: ph{2,3} -> ph{0,1} (full 64q x 128c, f32 via v_s) ----
  __syncthreads();
  float* red = (float*)v_s;   // 16384 f32: slot0 = [0,8192), slot1 = [8192,16384)
  if (ph >= 2) {
    if (hi == 0) { d_red[ph - 2][0][l31] = tot0; d_red[ph - 2][1][l31] = tot1; }
    float* dst = red + (size_t)(ph - 2) * 64 * 128;
    #pragma unroll
    for (int cb = 0; cb < 4; cb++)
      #pragma unroll
      for (int r = 0; r < 16; r++) {
        int row = (r & 3) + 8 * (r >> 2) + 4 * hi;
        dst[(size_t)row * 128 + cb * 32 + l31] = acc0[cb][r];
        dst[(size_t)(row + 32) * 128 + cb * 32 + l31] = acc1[cb][r];
      }
  }
  __syncthreads();
  // ---- step-1 add + step-2 cross-pair exchange (ph0 keeps q 0-31, ph1 keeps q 32-63) ----
  if (ph < 2) {
    tot0 += d_red[ph][0][l31];
    tot1 += d_red[ph][1][l31];
    const float* src = red + (size_t)ph * 64 * 128;
    #pragma unroll
    for (int cb = 0; cb < 4; cb++)
      #pragma unroll
      for (int r = 0; r < 16; r++) {
        int row = (r & 3) + 8 * (r >> 2) + 4 * hi;
        acc0[cb][r] += src[(size_t)row * 128 + cb * 32 + l31];
        acc1[cb][r] += src[(size_t)(row + 32) * 128 + cb * 32 + l31];
      }
    if (ph == 0) {
      if (hi == 0) d_x[0][l31] = tot1;
      #pragma unroll
      for (int cb = 0; cb < 4; cb++)
        #pragma unroll
        for (int r = 0; r < 16; r++) {
          int row = (r & 3) + 8 * (r >> 2) + 4 * hi;
          red[(size_t)(row + 32) * 128 + cb * 32 + l31] = acc1[cb][r];  // slot0 rows 32-63
        }
    } else {
      if (hi == 0) d_x[1][l31] = tot0;
      #pragma unroll
      for (int cb = 0; cb < 4; cb++)
        #pragma unroll
        for (int r = 0; r < 16; r++) {
          int row = (r & 3) + 8 * (r >> 2) + 4 * hi;
          red[8192 + (size_t)row * 128 + cb * 32 + l31] = acc0[cb][r];  // slot1 rows 0-31
        }
    }
  }
  __syncthreads();
  if (ph == 0) {
    float denom = tot0 + d_x[1][l31];       // full denom for q = l31
    if (hi == 0) d_inv[0][l31] = 1.0f / denom;
    #pragma unroll
    for (int cb = 0; cb < 4; cb++)
      #pragma unroll
      for (int r = 0; r < 16; r++) {
        int row = (r & 3) + 8 * (r >> 2) + 4 * hi;
        acc0[cb][r] += red[8192 + (size_t)row * 128 + cb * 32 + l31];
      }
  } else if (ph == 1) {
    float denom = tot1 + d_x[0][l31];       // full denom for q = 32 + l31
    if (hi == 0) d_inv[1][l31] = 1.0f / denom;
    #pragma unroll
    for (int cb = 0; cb < 4; cb++)
      #pragma unroll
      for (int r = 0; r < 16; r++) {
        int row = (r & 3) + 8 * (r >> 2) + 4 * hi;
        acc1[cb][r] += red[(size_t)(row + 32) * 128 + cb * 32 + l31];
      }
  }
  __syncthreads();
  // ---- normalized bf16 O -> LDS [64][128] with XOR chunk swizzle (first 16 KB of v_s) ----
  u16* Old = (u16*)v_s;
  if (ph == 0) {
    #pragma unroll
    for (int cb = 0; cb < 4; cb++)
      #pragma unroll
      for (int r = 0; r < 16; r++) {
        int row = (r & 3) + 8 * (r >> 2) + 4 * hi;
        int c = cb * 32 + l31;
        Old[row * 128 + (((c >> 3) ^ (row & 15)) << 3) + (c & 7)] =
            f2bf(acc0[cb][r] * d_inv[0][row]);
      }
  } else if (ph == 1) {
    #pragma unroll
    for (int cb = 0; cb < 4; cb++)
      #pragma unroll
      for (int r = 0; r < 16; r++) {
        int q = 32 + (r & 3) + 8 * (r >> 2) + 4 * hi;
        int c = cb * 32 + l31;
        Old[q * 128 + (((c >> 3) ^ (q & 15)) << 3) + (c & 7)] =
            f2bf(acc1[cb][r] * d_inv[1][(q - 32)]);
      }
  }
  __syncthreads();
  // ---- Wo A-frags loaded LATE (short live range; no epilogue spill) ----
  bf16x8 woF[8];
  {
    const float* wrow = Wo + (size_t)(w * 32 + l31) * CQ + hi * 8;
    #pragma unroll
    for (int kc8 = 0; kc8 < 8; kc8++) {
      f32x4 a = *(const f32x4*)(wrow + kc8 * 16);
      f32x4 c4 = *(const f32x4*)(wrow + kc8 * 16 + 4);
      u32x4 pk = { cvtpk(a[0], a[1]), cvtpk(a[2], a[3]),
                   cvtpk(c4[0], c4[1]), cvtpk(c4[2], c4[3]) };
      woF[kc8] = __builtin_bit_cast(bf16x8, pk);
    }
  }
  // ---- Wo GEMM: wave w -> out channels w*32..+32, all 64 n; D rows = o, cols = q ----
  float g = gamma[0];
  const float* xb = xq + (size_t)b * CQ * NPIX;
  float* ob = out + (size_t)b * CQ * NPIX;
  #pragma unroll
  for (int qb = 0; qb < 2; qb++) {
    f32x16 e = z;
    int q = qb * 32 + l31;
    #pragma unroll
    for (int kc8 = 0; kc8 < 8; kc8++) {
      int phys = (kc8 * 2 + hi) ^ (l31 & 15);
      bf16x8 of = *(const bf16x8*)(Old + q * 128 + phys * 8);
      e = __builtin_amdgcn_mfma_f32_32x32x16_bf16(woF[kc8], of, e, 0, 0, 0);
    }
    #pragma unroll
    for (int r = 0; r < 16; r++) {
      int o = w * 32 + (r & 3) + 8 * (r >> 2) + 4 * hi;
      size_t idx = (size_t)o * NPIX + q0 + qb * 32 + l31;
      ob[idx] = g * (e[r] + bos[o]) + xb[idx];
    }
  }
}

extern "C" void kernel_launch(void* const* d_in, const int* in_sizes, int n_in,
                              void* d_out, int out_size, void* d_ws, size_t ws_size,
                              hipStream_t stream) {
  const float* x4q  = (const float*)d_in[0];
  const float* x4kv = (const float*)d_in[1];
  const float* Wq   = (const float*)d_in[2];
  const float* bq   = (const float*)d_in[3];
  const float* Wk   = (const float*)d_in[4];
  const float* bk   = (const float*)d_in[5];
  const float* Wv   = (const float*)d_in[6];
  const float* bv   = (const float*)d_in[7];
  const float* Wo   = (const float*)d_in[8];
  const float* bo   = (const float*)d_in[9];
  const float* gamma = (const float*)d_in[10];
  float* out = (float*)d_out;

  u16* Qs = (u16*)d_ws;                               // 1 MB
  u16* Ks = Qs + (size_t)NB * NPIX * QDIM;            // 1 MB
  u16* Vt = Ks + (size_t)NB * NPIX * QDIM;            // 8 MB

  proj_qkv<<<dim3(NB * 64), dim3(256), 0, stream>>>(
      x4q, Wq, bq, x4kv, Wk, bk, Wv, bv, Qs, Ks, Vt);
  attn<<<dim3(NB * 64), dim3(256), 0, stream>>>(Qs, Ks, Vt, Wo, bo, gamma, x4q, out);
}